// Round 15
// baseline (324.040 us; speedup 1.0000x reference)
//
#include <hip/hip_runtime.h>
#include <hip/hip_bf16.h>

// Problem constants
#define S_    2048
#define DIM_  1024
#define H_    16
#define DH_   64
#define BOT_  256
#define NIMG_ 4
#define LI_   512
#define K_    256
#define IH_   4
#define ID_   16
#define MAXREL_ 64
#define NBUCK_ 129
#define GH_   8
#define IDH2_ 128   // 2*IH*ID

typedef short bf16x8 __attribute__((ext_vector_type(8)));
typedef float f32x4  __attribute__((ext_vector_type(4)));

__device__ __forceinline__ unsigned short f2bf(float x) {   // RNE float->bf16
    unsigned u = __float_as_uint(x);
    return (unsigned short)((u + 0x7fffu + ((u >> 16) & 1u)) >> 16);
}
__device__ __forceinline__ float bf2f(unsigned short h) {
    return __uint_as_float(((unsigned)h) << 16);
}

// Split-region element offsets (ushort units). W1 = [Wqkv_d;Wq;Wk] contiguous.
#define OFF_W1_    2097152
#define OFF_WQ_    2359296
#define OFF_WK_    2490368
#define OFF_WQKVU_ 2621440
#define OFF_WPD_   3407872
#define OFF_WPU_   3670016
#define NSPLIT_    3932160

// ---------------------------------------------------------------------------
// Fused hi/lo bf16 split of hidden + all 6 weight matrices (one launch).
// ---------------------------------------------------------------------------
__global__ __launch_bounds__(256) void split_all_kernel(
    const float* __restrict__ hid, const float* __restrict__ wqd,
    const float* __restrict__ wq,  const float* __restrict__ wk,
    const float* __restrict__ wqu, const float* __restrict__ wpd,
    const float* __restrict__ wpu,
    unsigned short* __restrict__ hi, unsigned short* __restrict__ lo)
{
    long e = ((long)blockIdx.x * 256 + threadIdx.x) * 4;
    if (e >= NSPLIT_) return;
    const float* src; long off;
    if (e < OFF_W1_)         { src = hid; off = 0; }
    else if (e < OFF_WQ_)    { src = wqd; off = OFF_W1_; }
    else if (e < OFF_WK_)    { src = wq;  off = OFF_WQ_; }
    else if (e < OFF_WQKVU_) { src = wk;  off = OFF_WK_; }
    else if (e < OFF_WPD_)   { src = wqu; off = OFF_WQKVU_; }
    else if (e < OFF_WPU_)   { src = wpd; off = OFF_WPD_; }
    else                     { src = wpu; off = OFF_WPU_; }
    float4 v = *(const float4*)(src + (e - off));
    ushort4 h, l;
    h.x = f2bf(v.x); l.x = f2bf(v.x - bf2f(h.x));
    h.y = f2bf(v.y); l.y = f2bf(v.y - bf2f(h.y));
    h.z = f2bf(v.z); l.z = f2bf(v.z - bf2f(h.z));
    h.w = f2bf(v.w); l.w = f2bf(v.w - bf2f(h.w));
    *(ushort4*)&hi[e] = h;
    *(ushort4*)&lo[e] = l;
}

// ---------------------------------------------------------------------------
// bf16x3 MFMA GEMM, 128x64 tile (large-N: qkv_u, p_u). fp32 out.
// ---------------------------------------------------------------------------
__global__ __launch_bounds__(256) void gemm_bf16x3(
    const unsigned short* __restrict__ Ah, const unsigned short* __restrict__ Al,
    const unsigned short* __restrict__ Bh, const unsigned short* __restrict__ Bl,
    const float* __restrict__ bias, const float* __restrict__ scale_ptr,
    float* __restrict__ Cf, int M, int N, int Kd)
{
    __shared__ unsigned short sAh[128 * 40], sAl[128 * 40];
    __shared__ unsigned short sBh[64 * 40],  sBl[64 * 40];
    int tid = threadIdx.x;
    int lane = tid & 63, wv = tid >> 6;
    int wr = wv >> 1, wc = wv & 1;
    int row0 = blockIdx.y * 128, col0 = blockIdx.x * 64;

    f32x4 acc[4][2];
#pragma unroll
    for (int i = 0; i < 4; i++)
#pragma unroll
        for (int j = 0; j < 2; j++) acc[i][j] = (f32x4){0.f, 0.f, 0.f, 0.f};

    int ar = tid >> 1, ac = (tid & 1) * 16;
    int br = tid >> 2, bc = (tid & 3) * 8;
    const unsigned short* gAh = Ah + (size_t)(row0 + ar) * Kd + ac;
    const unsigned short* gAl = Al + (size_t)(row0 + ar) * Kd + ac;
    const unsigned short* gBh = Bh + (size_t)(col0 + br) * Kd + bc;
    const unsigned short* gBl = Bl + (size_t)(col0 + br) * Kd + bc;
    int am = lane & 15, qk = (lane >> 4) * 8;

    for (int k0 = 0; k0 < Kd; k0 += 32) {
        __syncthreads();
        *(float4*)&sAh[ar * 40 + ac]     = *(const float4*)(gAh + k0);
        *(float4*)&sAh[ar * 40 + ac + 8] = *(const float4*)(gAh + k0 + 8);
        *(float4*)&sAl[ar * 40 + ac]     = *(const float4*)(gAl + k0);
        *(float4*)&sAl[ar * 40 + ac + 8] = *(const float4*)(gAl + k0 + 8);
        *(float4*)&sBh[br * 40 + bc]     = *(const float4*)(gBh + k0);
        *(float4*)&sBl[br * 40 + bc]     = *(const float4*)(gBl + k0);
        __syncthreads();

        bf16x8 ah[4], al[4], bh[2], bl[2];
#pragma unroll
        for (int rt = 0; rt < 4; rt++) {
            int r = wr * 64 + rt * 16 + am;
            ah[rt] = *(const bf16x8*)&sAh[r * 40 + qk];
            al[rt] = *(const bf16x8*)&sAl[r * 40 + qk];
        }
#pragma unroll
        for (int ct = 0; ct < 2; ct++) {
            int c = wc * 32 + ct * 16 + am;
            bh[ct] = *(const bf16x8*)&sBh[c * 40 + qk];
            bl[ct] = *(const bf16x8*)&sBl[c * 40 + qk];
        }
#pragma unroll
        for (int rt = 0; rt < 4; rt++)
#pragma unroll
            for (int ct = 0; ct < 2; ct++) {
                acc[rt][ct] = __builtin_amdgcn_mfma_f32_16x16x32_bf16(ah[rt], bh[ct], acc[rt][ct], 0, 0, 0);
                acc[rt][ct] = __builtin_amdgcn_mfma_f32_16x16x32_bf16(ah[rt], bl[ct], acc[rt][ct], 0, 0, 0);
                acc[rt][ct] = __builtin_amdgcn_mfma_f32_16x16x32_bf16(al[rt], bh[ct], acc[rt][ct], 0, 0, 0);
            }
    }

    float scl = scale_ptr ? *scale_ptr : 1.0f;
    int rq = (lane >> 4) * 4;
#pragma unroll
    for (int rt = 0; rt < 4; rt++)
#pragma unroll
        for (int ct = 0; ct < 2; ct++) {
            int col = col0 + wc * 32 + ct * 16 + am;
            float bz = bias ? bias[col] : 0.0f;
#pragma unroll
            for (int rg = 0; rg < 4; rg++) {
                int row = row0 + wr * 64 + rt * 16 + rq + rg;
                Cf[(size_t)row * N + col] = (acc[rt][ct][rg] + bz) * scl;
            }
        }
}

// ---------------------------------------------------------------------------
// bf16x3 MFMA GEMM, 64x64 tile (gemm1 N=512 split epilogue, p_d N=256).
// ---------------------------------------------------------------------------
__global__ __launch_bounds__(256) void gemm64_bf16x3(
    const unsigned short* __restrict__ Ah, const unsigned short* __restrict__ Al,
    const unsigned short* __restrict__ Bh, const unsigned short* __restrict__ Bl,
    const float* __restrict__ bias_lo, const float* __restrict__ bias_hi,
    float* __restrict__ Cf, unsigned short* __restrict__ Chi,
    unsigned short* __restrict__ Clo, int M, int N, int Kd, int split_col)
{
    __shared__ unsigned short sAh[64 * 40], sAl[64 * 40];
    __shared__ unsigned short sBh[64 * 40], sBl[64 * 40];
    int tid = threadIdx.x;
    int lane = tid & 63, wv = tid >> 6;
    int wr = wv >> 1, wc = wv & 1;          // wave 32x32
    int row0 = blockIdx.y * 64, col0 = blockIdx.x * 64;

    f32x4 acc[2][2];
#pragma unroll
    for (int i = 0; i < 2; i++)
#pragma unroll
        for (int j = 0; j < 2; j++) acc[i][j] = (f32x4){0.f, 0.f, 0.f, 0.f};

    int sr = tid >> 2, sc = (tid & 3) * 8;
    const unsigned short* gAh = Ah + (size_t)(row0 + sr) * Kd + sc;
    const unsigned short* gAl = Al + (size_t)(row0 + sr) * Kd + sc;
    const unsigned short* gBh = Bh + (size_t)(col0 + sr) * Kd + sc;
    const unsigned short* gBl = Bl + (size_t)(col0 + sr) * Kd + sc;
    int am = lane & 15, qk = (lane >> 4) * 8;

    for (int k0 = 0; k0 < Kd; k0 += 32) {
        __syncthreads();
        *(float4*)&sAh[sr * 40 + sc] = *(const float4*)(gAh + k0);
        *(float4*)&sAl[sr * 40 + sc] = *(const float4*)(gAl + k0);
        *(float4*)&sBh[sr * 40 + sc] = *(const float4*)(gBh + k0);
        *(float4*)&sBl[sr * 40 + sc] = *(const float4*)(gBl + k0);
        __syncthreads();

        bf16x8 ah[2], al[2], bh[2], bl[2];
#pragma unroll
        for (int rt = 0; rt < 2; rt++) {
            int r = wr * 32 + rt * 16 + am;
            ah[rt] = *(const bf16x8*)&sAh[r * 40 + qk];
            al[rt] = *(const bf16x8*)&sAl[r * 40 + qk];
        }
#pragma unroll
        for (int ct = 0; ct < 2; ct++) {
            int c = wc * 32 + ct * 16 + am;
            bh[ct] = *(const bf16x8*)&sBh[c * 40 + qk];
            bl[ct] = *(const bf16x8*)&sBl[c * 40 + qk];
        }
#pragma unroll
        for (int rt = 0; rt < 2; rt++)
#pragma unroll
            for (int ct = 0; ct < 2; ct++) {
                acc[rt][ct] = __builtin_amdgcn_mfma_f32_16x16x32_bf16(ah[rt], bh[ct], acc[rt][ct], 0, 0, 0);
                acc[rt][ct] = __builtin_amdgcn_mfma_f32_16x16x32_bf16(ah[rt], bl[ct], acc[rt][ct], 0, 0, 0);
                acc[rt][ct] = __builtin_amdgcn_mfma_f32_16x16x32_bf16(al[rt], bh[ct], acc[rt][ct], 0, 0, 0);
            }
    }

    int rq = (lane >> 4) * 4;
#pragma unroll
    for (int rt = 0; rt < 2; rt++)
#pragma unroll
        for (int ct = 0; ct < 2; ct++) {
            int col = col0 + wc * 32 + ct * 16 + am;
#pragma unroll
            for (int rg = 0; rg < 4; rg++) {
                int row = row0 + wr * 32 + rt * 16 + rq + rg;
                float v = acc[rt][ct][rg];
                if (col < split_col) {
                    if (bias_lo) v += bias_lo[col];
                    size_t idx = (size_t)row * split_col + col;
                    unsigned short hh = f2bf(v);
                    Chi[idx] = hh;
                    Clo[idx] = f2bf(v - bf2f(hh));
                } else {
                    if (bias_hi) v += bias_hi[col - split_col];
                    Cf[(size_t)row * (N - split_col) + col - split_col] = v;
                }
            }
        }
}

// ---------------------------------------------------------------------------
// RoPE applied in-place to q and k slices of qkv[S,3072].
// ---------------------------------------------------------------------------
__global__ __launch_bounds__(256) void rope_kernel(
    float* __restrict__ qkv, const float* __restrict__ rope)
{
    int idx = blockIdx.x * blockDim.x + threadIdx.x;  // S*H*32 total
    if (idx >= S_ * H_ * 32) return;
    int d = idx & 31;
    int h = (idx >> 5) & (H_ - 1);
    int s = idx >> 9;
    float r = rope[s * 32 + d];
    float c = cosf(r), sn = sinf(r);
    size_t base = (size_t)s * 3072 + h * 64 + d;
    float q1 = qkv[base], q2 = qkv[base + 32];
    qkv[base]      = q1 * c - q2 * sn;
    qkv[base + 32] = q2 * c + q1 * sn;
    float k1 = qkv[base + 1024], k2 = qkv[base + 1024 + 32];
    qkv[base + 1024]      = k1 * c - k2 * sn;
    qkv[base + 1024 + 32] = k2 * c + k1 * sn;
}

// ---------------------------------------------------------------------------
// Fused index scores + top-K membership v5: ONE ROW PER BLOCK (2048 blocks).
// Occupancy fix: R12/R14 ran 512 blocks = 2 blocks/CU (17% occ) with 28
// barriers/block — latency-bound regardless of bank conflicts (R12 vs R14
// A/B: 4.2M vs 6.3M conflicts, same 43 us). Now: qI row in LDS (broadcast
// reads), each thread scores keys tid and tid+256 reading kI DIRECT from
// global (unroll 1 on key loop keeps VGPR ~100, unlike R13's 240), one
// barrier total; select runs on wave 0 barrier-free (intra-wave LDS ops are
// program-ordered on GCN). Score math bit-identical -> selection unchanged.
// ---------------------------------------------------------------------------
__global__ __launch_bounds__(256) void score_topk_kernel(
    const float* __restrict__ qIk,
    const int* __restrict__ coords, const float* __restrict__ rpe_table,
    const float* __restrict__ W1g, const float* __restrict__ b1g,
    const float* __restrict__ W2g, const float* __restrict__ b2g,
    unsigned* __restrict__ selmask)
{
    __shared__ float sqI[IDH2_];
    __shared__ unsigned skeys[LI_];
    __shared__ int hist[256];
    __shared__ float srpe[NBUCK_ * IH_];
    __shared__ float sW1[GH_ * IH_], sb1[GH_], sW2[IH_ * GH_], sb2[IH_];

    int tid = threadIdx.x;
    int row = blockIdx.x;
    int n   = row >> 9;

    for (int i = tid; i < NBUCK_ * IH_; i += 256) srpe[i] = rpe_table[i];
    if (tid < 32) sW1[tid] = W1g[tid];
    else if (tid < 64) sW2[tid - 32] = W2g[tid - 32];
    else if (tid < 72) sb1[tid - 64] = b1g[tid - 64];
    else if (tid < 76) sb2[tid - 72] = b2g[tid - 72];
    if (tid < 32)
        *(float4*)&sqI[tid * 4] = *(const float4*)(qIk + (size_t)row * 256 + tid * 4);
    int pq = coords[row * 2 + 1];
    __syncthreads();

    // ---- score phase: thread handles keys tid and tid+256 ----
#pragma unroll 1
    for (int kk = 0; kk < 2; kk++) {
        int kg   = kk * 256 + tid;
        int krow = n * LI_ + kg;
        const float* kp = qIk + (size_t)krow * 256 + 128;
        float dh[8];
#pragma unroll
        for (int hh = 0; hh < 8; hh++) {
            float acc = 0.0f;
#pragma unroll
            for (int d = 0; d < 16; d += 4) {
                float4 kv = *(const float4*)(kp + hh * 16 + d);
                acc += sqI[hh * 16 + d + 0] * kv.x + sqI[hh * 16 + d + 1] * kv.y +
                       sqI[hh * 16 + d + 2] * kv.z + sqI[hh * 16 + d + 3] * kv.w;
            }
            dh[hh] = acc;
        }
        int pk = coords[krow * 2 + 1];
        int rel = pq - pk;
        rel = rel < -MAXREL_ ? -MAXREL_ : (rel > MAXREL_ ? MAXREL_ : rel);
        const float* rp = srpe + (rel + MAXREL_) * IH_;
        float t1[GH_];
#pragma unroll
        for (int g = 0; g < GH_; g++) t1[g] = sb1[g];
#pragma unroll
        for (int j = 0; j < IH_; j++) {
            float gate = dh[IH_ + j] + rp[j];
#pragma unroll
            for (int g = 0; g < GH_; g++) t1[g] += gate * sW1[g * IH_ + j];
        }
#pragma unroll
        for (int g = 0; g < GH_; g++) t1[g] = fmaxf(t1[g], 0.0f);
        float score = 0.0f;
#pragma unroll
        for (int j = 0; j < IH_; j++) {
            float t2 = sb2[j];
#pragma unroll
            for (int g = 0; g < GH_; g++) t2 += t1[g] * sW2[j * GH_ + g];
            float sg = 1.0f / (1.0f + expf(-t2));
            float rs = fmaxf(dh[j] + rp[j], 0.0f);
            score += rs * sg;
        }
        unsigned bits = __float_as_uint(score);
        skeys[kg] = (bits & 0x80000000u) ? ~bits : (bits | 0x80000000u);
    }
    __syncthreads();          // last barrier: skeys complete
    if (tid >= 64) return;    // waves 1-3 exit; wave 0 selects barrier-free

    int lane = tid;
    unsigned pref = 0u;
    int kcur = K_;
    const unsigned himask[4] = {0u, 0xFF000000u, 0xFFFF0000u, 0xFFFFFF00u};
#pragma unroll
    for (int pass = 0; pass < 4; pass++) {
        int shift = 24 - pass * 8;
        unsigned hm = himask[pass];
        *(int4*)&hist[4 * lane] = make_int4(0, 0, 0, 0);
#pragma unroll
        for (int c = 0; c < 8; c++) {
            unsigned key = skeys[c * 64 + lane];
            if ((key & hm) == pref) atomicAdd(&hist[(key >> shift) & 255], 1);
        }
        int4 b4 = *(const int4*)&hist[4 * lane];
        int b[4] = {b4.x, b4.y, b4.z, b4.w};
        int t = b[0] + b[1] + b[2] + b[3];
        int Ssum = t;
#pragma unroll
        for (int off = 1; off < 64; off <<= 1) {
            int u = __shfl_down(Ssum, off, 64);
            if (lane + off < 64) Ssum += u;
        }
        int E = Ssum - t;
        int cs[5];
        cs[4] = E;
        cs[3] = b[3] + E;
        cs[2] = b[2] + cs[3];
        cs[1] = b[1] + cs[2];
        cs[0] = b[0] + cs[1];
        bool found = false;
        unsigned cpref = 0u; int ck = 0;
#pragma unroll
        for (int j = 0; j < 4; j++) {
            if (!found && cs[j] >= kcur && cs[j + 1] < kcur) {
                found = true;
                cpref = pref | ((unsigned)(4 * lane + j) << shift);
                ck = kcur - cs[j + 1];
            }
        }
        unsigned long long bm = __ballot(found);
        int src = __ffsll((long long)bm) - 1;
        pref = (unsigned)__shfl((int)cpref, src, 64);
        kcur = __shfl(ck, src, 64);
    }
    unsigned Tu = pref;

    unsigned long long bg[8], be[8];
#pragma unroll
    for (int c = 0; c < 8; c++) {
        unsigned key = skeys[c * 64 + lane];
        bg[c] = __ballot(key > Tu);
        be[c] = __ballot(key == Tu);
    }
    if (lane < 16) {
        int total_gt = 0;
#pragma unroll
        for (int c = 0; c < 8; c++) total_gt += __popcll(bg[c]);
        int base = 0;
#pragma unroll
        for (int c = 0; c < 8; c++) {
            if (2 * c < lane)     base += __popc((unsigned)be[c]);
            if (2 * c + 1 < lane) base += __popc((unsigned)(be[c] >> 32));
        }
        unsigned gw = (unsigned)(bg[lane >> 1] >> (32 * (lane & 1)));
        unsigned ew = (unsigned)(be[lane >> 1] >> (32 * (lane & 1)));
        int ne = K_ - total_gt - base;
        int pc = __popc(ew);
        int m = ne < 0 ? 0 : (ne > pc ? pc : ne);
        while (pc > m) { ew ^= (1u << (31 - __clz(ew))); pc--; }
        selmask[(size_t)row * 16 + lane] = gw | ew;
    }
}

// ---------------------------------------------------------------------------
// Dense-masked attention v4: full MFMA bf16x3 (R12/R14-passing, unchanged).
// ---------------------------------------------------------------------------
__global__ __launch_bounds__(256) void attn_kernel(
    const float* __restrict__ qkv, const unsigned* __restrict__ selmask,
    unsigned short* __restrict__ outh, unsigned short* __restrict__ outl)
{
    __shared__ unsigned short Qh[64 * 72],  Ql[64 * 72];   // [q][d]
    __shared__ unsigned short KPh[64 * 72], KPl[64 * 72];  // K [key][d] -> P [q][key]
    __shared__ unsigned short VTh[64 * 72], VTl[64 * 72];  // V^T [d][key]
    __shared__ unsigned Ms[64][16];

    int b  = blockIdx.x;
    int qt = b >> 6;                 // XCD swizzle: qt in high bits
    int nh = b & 63;
    int h  = nh & 15;
    int n  = nh >> 4;
    int tid = threadIdx.x;
    int lane = tid & 63, w = tid >> 6;
    int lane15 = lane & 15, quad = lane >> 4;
    int q0 = n * LI_ + qt * 64;

    for (int i = tid; i < 64 * 16; i += 256)
        Ms[i >> 4][i & 15] = selmask[(size_t)(q0 + (i >> 4)) * 16 + (i & 15)];

    // stage Q once: row r, 16 d's; scale 1/8 then split (exact scaling)
    {
        int r = tid >> 2, c0 = (tid & 3) * 16;
        const float* src = qkv + (size_t)(q0 + r) * 3072 + h * 64 + c0;
        unsigned short hb[16], lb[16];
#pragma unroll
        for (int j = 0; j < 16; j += 4) {
            float4 v = *(const float4*)(src + j);
            float f[4] = {v.x * 0.125f, v.y * 0.125f, v.z * 0.125f, v.w * 0.125f};
#pragma unroll
            for (int t = 0; t < 4; t++) {
                unsigned short hh = f2bf(f[t]);
                hb[j + t] = hh;
                lb[j + t] = f2bf(f[t] - bf2f(hh));
            }
        }
        *(uint4*)&Qh[r * 72 + c0]     = *(uint4*)&hb[0];
        *(uint4*)&Qh[r * 72 + c0 + 8] = *(uint4*)&hb[8];
        *(uint4*)&Ql[r * 72 + c0]     = *(uint4*)&lb[0];
        *(uint4*)&Ql[r * 72 + c0 + 8] = *(uint4*)&lb[8];
    }

    f32x4 o_acc[4];
#pragma unroll
    for (int i = 0; i < 4; i++) o_acc[i] = (f32x4){0.f, 0.f, 0.f, 0.f};
    float rsum[4] = {};

    for (int kt = 0; kt < 8; kt++) {
        __syncthreads();   // prev PV reads of KP/VT done
        // stage K [key][d] hi/lo
        {
            int r = tid >> 2, c0 = (tid & 3) * 16;
            const float* src = qkv + (size_t)(n * LI_ + kt * 64 + r) * 3072 + 1024 + h * 64 + c0;
            unsigned short hb[16], lb[16];
#pragma unroll
            for (int j = 0; j < 16; j += 4) {
                float4 v = *(const float4*)(src + j);
                float f[4] = {v.x, v.y, v.z, v.w};
#pragma unroll
                for (int t = 0; t < 4; t++) {
                    unsigned short hh = f2bf(f[t]);
                    hb[j + t] = hh;
                    lb[j + t] = f2bf(f[t] - bf2f(hh));
                }
            }
            *(uint4*)&KPh[r * 72 + c0]     = *(uint4*)&hb[0];
            *(uint4*)&KPh[r * 72 + c0 + 8] = *(uint4*)&hb[8];
            *(uint4*)&KPl[r * 72 + c0]     = *(uint4*)&lb[0];
            *(uint4*)&KPl[r * 72 + c0 + 8] = *(uint4*)&lb[8];
        }
        // stage V^T [d][key]: thread owns column d = lane (per-wave 16 keys),
        // coalesced reads (lanes span d), contiguous row writes
        {
            int d = lane;
            int k0 = w * 16;
            const float* src = qkv + (size_t)(n * LI_ + kt * 64 + k0) * 3072 + 2048 + h * 64 + d;
            unsigned short hb[16], lb[16];
#pragma unroll
            for (int j = 0; j < 16; j++) {
                float f = src[(size_t)j * 3072];
                unsigned short hh = f2bf(f);
                hb[j] = hh;
                lb[j] = f2bf(f - bf2f(hh));
            }
            *(uint4*)&VTh[d * 72 + k0]     = *(uint4*)&hb[0];
            *(uint4*)&VTh[d * 72 + k0 + 8] = *(uint4*)&hb[8];
            *(uint4*)&VTl[d * 72 + k0]     = *(uint4*)&lb[0];
            *(uint4*)&VTl[d * 72 + k0 + 8] = *(uint4*)&lb[8];
        }
        __syncthreads();

        // QK: wave w computes q-tile w vs all 4 key-tiles, bf16x3
        f32x4 s_acc[4];
#pragma unroll
        for (int nt = 0; nt < 4; nt++) s_acc[nt] = (f32x4){0.f, 0.f, 0.f, 0.f};
        {
            bf16x8 qfh[2], qfl[2];
#pragma unroll
            for (int ks = 0; ks < 2; ks++) {
                qfh[ks] = *(const bf16x8*)&Qh[(16 * w + lane15) * 72 + ks * 32 + quad * 8];
                qfl[ks] = *(const bf16x8*)&Ql[(16 * w + lane15) * 72 + ks * 32 + quad * 8];
            }
#pragma unroll
            for (int nt = 0; nt < 4; nt++) {
#pragma unroll
                for (int ks = 0; ks < 2; ks++) {
                    bf16x8 kfh = *(const bf16x8*)&KPh[(16 * nt + lane15) * 72 + ks * 32 + quad * 8];
                    bf16x8 kfl = *(const bf16x8*)&KPl[(16 * nt + lane15) * 72 + ks * 32 + quad * 8];
                    s_acc[nt] = __builtin_amdgcn_mfma_f32_16x16x32_bf16(qfh[ks], kfh, s_acc[nt], 0, 0, 0);
                    s_acc[nt] = __builtin_amdgcn_mfma_f32_16x16x32_bf16(qfh[ks], kfl, s_acc[nt], 0, 0, 0);
                    s_acc[nt] = __builtin_amdgcn_mfma_f32_16x16x32_bf16(qfl[ks], kfh, s_acc[nt], 0, 0, 0);
                }
            }
        }
        __syncthreads();   // all K frag reads done before P overwrite

        // softmax (C-layout: row q = quad*4+reg, col key = lane15) + P split
#pragma unroll
        for (int nt = 0; nt < 4; nt++) {
            int kb = kt * 64 + nt * 16 + lane15;
            int wi = kb >> 5, bit = kb & 31;
#pragma unroll
            for (int reg = 0; reg < 4; reg++) {
                int qloc = 16 * w + quad * 4 + reg;
                unsigned mw = Ms[qloc][wi];
                float p = ((mw >> bit) & 1u) ? __expf(s_acc[nt][reg]) : 0.0f;
                rsum[reg] += p;
                unsigned short ph = f2bf(p);
                KPh[qloc * 72 + nt * 16 + lane15] = ph;
                KPl[qloc * 72 + nt * 16 + lane15] = f2bf(p - bf2f(ph));
            }
        }
        __syncthreads();

        // PV: A = P [q][key], B = V^T [d][key], bf16x3
        {
            bf16x8 pfh[2], pfl[2];
#pragma unroll
            for (int ks = 0; ks < 2; ks++) {
                pfh[ks] = *(const bf16x8*)&KPh[(16 * w + lane15) * 72 + ks * 32 + quad * 8];
                pfl[ks] = *(const bf16x8*)&KPl[(16 * w + lane15) * 72 + ks * 32 + quad * 8];
            }
#pragma unroll
            for (int dt = 0; dt < 4; dt++) {
#pragma unroll
                for (int ks = 0; ks < 2; ks++) {
                    bf16x8 vfh = *(const bf16x8*)&VTh[(16 * dt + lane15) * 72 + ks * 32 + quad * 8];
                    bf16x8 vfl = *(const bf16x8*)&VTl[(16 * dt + lane15) * 72 + ks * 32 + quad * 8];
                    o_acc[dt] = __builtin_amdgcn_mfma_f32_16x16x32_bf16(pfh[ks], vfh, o_acc[dt], 0, 0, 0);
                    o_acc[dt] = __builtin_amdgcn_mfma_f32_16x16x32_bf16(pfh[ks], vfl, o_acc[dt], 0, 0, 0);
                    o_acc[dt] = __builtin_amdgcn_mfma_f32_16x16x32_bf16(pfl[ks], vfh, o_acc[dt], 0, 0, 0);
                }
            }
        }
    }

    // row sums: reduce over the 16 lanes (lane15) sharing each q row
#pragma unroll
    for (int reg = 0; reg < 4; reg++) {
        rsum[reg] += __shfl_xor(rsum[reg], 1, 64);
        rsum[reg] += __shfl_xor(rsum[reg], 2, 64);
        rsum[reg] += __shfl_xor(rsum[reg], 4, 64);
        rsum[reg] += __shfl_xor(rsum[reg], 8, 64);
    }

    // epilogue: normalize, split hi/lo, store (C-layout: row=quad*4+reg, col=lane15)
#pragma unroll
    for (int dt = 0; dt < 4; dt++) {
#pragma unroll
        for (int reg = 0; reg < 4; reg++) {
            float v = o_acc[dt][reg] / rsum[reg];
            size_t ob = (size_t)(q0 + 16 * w + quad * 4 + reg) * 1024 + h * 64 + 16 * dt + lane15;
            unsigned short hh = f2bf(v);
            outh[ob] = hh;
            outl[ob] = f2bf(v - bf2f(hh));
        }
    }
}

// ---------------------------------------------------------------------------
extern "C" void kernel_launch(void* const* d_in, const int* in_sizes, int n_in,
                              void* d_out, int out_size, void* d_ws, size_t ws_size,
                              hipStream_t stream)
{
    const float* hidden  = (const float*)d_in[0];
    const int*   coords  = (const int*)d_in[1];
    const float* rope    = (const float*)d_in[3];
    const float* Wq_idx  = (const float*)d_in[4];
    const float* Wk_idx  = (const float*)d_in[5];
    const float* W1g     = (const float*)d_in[6];
    const float* b1g     = (const float*)d_in[7];
    const float* W2g     = (const float*)d_in[8];
    const float* b2g     = (const float*)d_in[9];
    const float* rpe     = (const float*)d_in[10];
    const float* Wqkv_d  = (const float*)d_in[11];
    const float* bqkv_d  = (const float*)d_in[12];
    const float* Wqkv_u  = (const float*)d_in[13];
    const float* bqkv_u  = (const float*)d_in[14];
    const float* Wp_d    = (const float*)d_in[15];
    const float* bp_d    = (const float*)d_in[16];
    const float* Wp_u    = (const float*)d_in[17];
    const float* bp_u    = (const float*)d_in[18];
    const float* scaler  = (const float*)d_in[19];
    float* out = (float*)d_out;

    unsigned short* sp_hi  = (unsigned short*)d_ws;
    unsigned short* sp_lo  = sp_hi + NSPLIT_;
    unsigned short* mid_hi = sp_lo + NSPLIT_;
    unsigned short* mid_lo = mid_hi + (size_t)S_ * BOT_;
    float* qkv = (float*)(mid_lo + (size_t)S_ * BOT_);
    float* qIk = qkv + (size_t)S_ * 3 * DIM_;
    unsigned* selmask = (unsigned*)(qIk + (size_t)S_ * 256);

    // 0) split hidden + all weights into hi/lo bf16
    split_all_kernel<<<(NSPLIT_ / 4 + 255) / 256, 256, 0, stream>>>(
        hidden, Wqkv_d, Wq_idx, Wk_idx, Wqkv_u, Wp_d, Wp_u, sp_hi, sp_lo);

    // 1) fused gemm1: hidden @ [Wqkv_d;Wq;Wk]^T -> mid(hi/lo) + qIk(fp32)
    gemm64_bf16x3<<<dim3(512 / 64, S_ / 64), 256, 0, stream>>>(
        sp_hi, sp_lo, sp_hi + OFF_W1_, sp_lo + OFF_W1_,
        bqkv_d, nullptr, qIk, mid_hi, mid_lo, S_, 512, DIM_, 256);

    // 2) qkv = mid @ Wqkv_u^T + b (fp32)
    gemm_bf16x3<<<dim3(3 * DIM_ / 64, S_ / 128), 256, 0, stream>>>(
        mid_hi, mid_lo, sp_hi + OFF_WQKVU_, sp_lo + OFF_WQKVU_,
        bqkv_u, nullptr, qkv, S_, 3 * DIM_, BOT_);

    // 3) RoPE on q,k in place
    rope_kernel<<<(S_ * H_ * 32) / 256, 256, 0, stream>>>(qkv, rope);

    // 4) fused index scores + top-k membership (1 row/block)
    score_topk_kernel<<<S_, 256, 0, stream>>>(
        qIk, coords, rpe, W1g, b1g, W2g, b2g, selmask);

    // 5) MFMA attention (emits attout hi/lo into hidden's split slots)
    attn_kernel<<<NIMG_ * H_ * 8, 256, 0, stream>>>(qkv, selmask, sp_hi, sp_lo);

    // 6) mid2 = attout @ Wp_d^T + b (hi/lo)
    gemm64_bf16x3<<<dim3(BOT_ / 64, S_ / 64), 256, 0, stream>>>(
        sp_hi, sp_lo, sp_hi + OFF_WPD_, sp_lo + OFF_WPD_,
        bp_d, nullptr, nullptr, mid_hi, mid_lo, S_, BOT_, DIM_, BOT_);

    // 7) out = mid2 @ Wp_u^T + b, *scaler (fp32)
    gemm_bf16x3<<<dim3(DIM_ / 64, S_ / 128), 256, 0, stream>>>(
        mid_hi, mid_lo, sp_hi + OFF_WPU_, sp_lo + OFF_WPU_,
        bp_u, scaler, out, S_, DIM_, BOT_);
}

// Round 16
// 251.421 us; speedup vs baseline: 1.2888x; 1.2888x over previous
//
#include <hip/hip_runtime.h>
#include <hip/hip_bf16.h>

// Problem constants
#define S_    2048
#define DIM_  1024
#define H_    16
#define DH_   64
#define BOT_  256
#define NIMG_ 4
#define LI_   512
#define K_    256
#define IH_   4
#define ID_   16
#define MAXREL_ 64
#define NBUCK_ 129
#define GH_   8
#define IDH2_ 128   // 2*IH*ID

typedef short bf16x8 __attribute__((ext_vector_type(8)));
typedef float f32x4  __attribute__((ext_vector_type(4)));

__device__ __forceinline__ unsigned short f2bf(float x) {   // RNE float->bf16
    unsigned u = __float_as_uint(x);
    return (unsigned short)((u + 0x7fffu + ((u >> 16) & 1u)) >> 16);
}
__device__ __forceinline__ float bf2f(unsigned short h) {
    return __uint_as_float(((unsigned)h) << 16);
}

// Split-region element offsets (ushort units). W1 = [Wqkv_d;Wq;Wk] contiguous.
#define OFF_W1_    2097152
#define OFF_WQ_    2359296
#define OFF_WK_    2490368
#define OFF_WQKVU_ 2621440
#define OFF_WPD_   3407872
#define OFF_WPU_   3670016
#define NSPLIT_    3932160

// ---------------------------------------------------------------------------
// Fused hi/lo bf16 split of hidden + all 6 weight matrices (one launch).
// ---------------------------------------------------------------------------
__global__ __launch_bounds__(256) void split_all_kernel(
    const float* __restrict__ hid, const float* __restrict__ wqd,
    const float* __restrict__ wq,  const float* __restrict__ wk,
    const float* __restrict__ wqu, const float* __restrict__ wpd,
    const float* __restrict__ wpu,
    unsigned short* __restrict__ hi, unsigned short* __restrict__ lo)
{
    long e = ((long)blockIdx.x * 256 + threadIdx.x) * 4;
    if (e >= NSPLIT_) return;
    const float* src; long off;
    if (e < OFF_W1_)         { src = hid; off = 0; }
    else if (e < OFF_WQ_)    { src = wqd; off = OFF_W1_; }
    else if (e < OFF_WK_)    { src = wq;  off = OFF_WQ_; }
    else if (e < OFF_WQKVU_) { src = wk;  off = OFF_WK_; }
    else if (e < OFF_WPD_)   { src = wqu; off = OFF_WQKVU_; }
    else if (e < OFF_WPU_)   { src = wpd; off = OFF_WPD_; }
    else                     { src = wpu; off = OFF_WPU_; }
    float4 v = *(const float4*)(src + (e - off));
    ushort4 h, l;
    h.x = f2bf(v.x); l.x = f2bf(v.x - bf2f(h.x));
    h.y = f2bf(v.y); l.y = f2bf(v.y - bf2f(h.y));
    h.z = f2bf(v.z); l.z = f2bf(v.z - bf2f(h.z));
    h.w = f2bf(v.w); l.w = f2bf(v.w - bf2f(h.w));
    *(ushort4*)&hi[e] = h;
    *(ushort4*)&lo[e] = l;
}

// ---------------------------------------------------------------------------
// bf16x3 MFMA GEMM, 128x64 tile (large-N: qkv_u, p_u). fp32 out. (unchanged)
// ---------------------------------------------------------------------------
__global__ __launch_bounds__(256) void gemm_bf16x3(
    const unsigned short* __restrict__ Ah, const unsigned short* __restrict__ Al,
    const unsigned short* __restrict__ Bh, const unsigned short* __restrict__ Bl,
    const float* __restrict__ bias, const float* __restrict__ scale_ptr,
    float* __restrict__ Cf, int M, int N, int Kd)
{
    __shared__ unsigned short sAh[128 * 40], sAl[128 * 40];
    __shared__ unsigned short sBh[64 * 40],  sBl[64 * 40];
    int tid = threadIdx.x;
    int lane = tid & 63, wv = tid >> 6;
    int wr = wv >> 1, wc = wv & 1;
    int row0 = blockIdx.y * 128, col0 = blockIdx.x * 64;

    f32x4 acc[4][2];
#pragma unroll
    for (int i = 0; i < 4; i++)
#pragma unroll
        for (int j = 0; j < 2; j++) acc[i][j] = (f32x4){0.f, 0.f, 0.f, 0.f};

    int ar = tid >> 1, ac = (tid & 1) * 16;
    int br = tid >> 2, bc = (tid & 3) * 8;
    const unsigned short* gAh = Ah + (size_t)(row0 + ar) * Kd + ac;
    const unsigned short* gAl = Al + (size_t)(row0 + ar) * Kd + ac;
    const unsigned short* gBh = Bh + (size_t)(col0 + br) * Kd + bc;
    const unsigned short* gBl = Bl + (size_t)(col0 + br) * Kd + bc;
    int am = lane & 15, qk = (lane >> 4) * 8;

    for (int k0 = 0; k0 < Kd; k0 += 32) {
        __syncthreads();
        *(float4*)&sAh[ar * 40 + ac]     = *(const float4*)(gAh + k0);
        *(float4*)&sAh[ar * 40 + ac + 8] = *(const float4*)(gAh + k0 + 8);
        *(float4*)&sAl[ar * 40 + ac]     = *(const float4*)(gAl + k0);
        *(float4*)&sAl[ar * 40 + ac + 8] = *(const float4*)(gAl + k0 + 8);
        *(float4*)&sBh[br * 40 + bc]     = *(const float4*)(gBh + k0);
        *(float4*)&sBl[br * 40 + bc]     = *(const float4*)(gBl + k0);
        __syncthreads();

        bf16x8 ah[4], al[4], bh[2], bl[2];
#pragma unroll
        for (int rt = 0; rt < 4; rt++) {
            int r = wr * 64 + rt * 16 + am;
            ah[rt] = *(const bf16x8*)&sAh[r * 40 + qk];
            al[rt] = *(const bf16x8*)&sAl[r * 40 + qk];
        }
#pragma unroll
        for (int ct = 0; ct < 2; ct++) {
            int c = wc * 32 + ct * 16 + am;
            bh[ct] = *(const bf16x8*)&sBh[c * 40 + qk];
            bl[ct] = *(const bf16x8*)&sBl[c * 40 + qk];
        }
#pragma unroll
        for (int rt = 0; rt < 4; rt++)
#pragma unroll
            for (int ct = 0; ct < 2; ct++) {
                acc[rt][ct] = __builtin_amdgcn_mfma_f32_16x16x32_bf16(ah[rt], bh[ct], acc[rt][ct], 0, 0, 0);
                acc[rt][ct] = __builtin_amdgcn_mfma_f32_16x16x32_bf16(ah[rt], bl[ct], acc[rt][ct], 0, 0, 0);
                acc[rt][ct] = __builtin_amdgcn_mfma_f32_16x16x32_bf16(al[rt], bh[ct], acc[rt][ct], 0, 0, 0);
            }
    }

    float scl = scale_ptr ? *scale_ptr : 1.0f;
    int rq = (lane >> 4) * 4;
#pragma unroll
    for (int rt = 0; rt < 4; rt++)
#pragma unroll
        for (int ct = 0; ct < 2; ct++) {
            int col = col0 + wc * 32 + ct * 16 + am;
            float bz = bias ? bias[col] : 0.0f;
#pragma unroll
            for (int rg = 0; rg < 4; rg++) {
                int row = row0 + wr * 64 + rt * 16 + rq + rg;
                Cf[(size_t)row * N + col] = (acc[rt][ct][rg] + bz) * scl;
            }
        }
}

// ---------------------------------------------------------------------------
// bf16x3 MFMA GEMM, 64x64 tile, BK=64 (gemm1 N=512 split epilogue, p_d N=256).
// BK 32->64: halves barrier count (16 sync-pairs for K=1024), 24 MFMA/wave/iter.
// LDS stride 72 (144 B): frag-read banks 4r mod 32 -> 2-way (free). 36.9 KB.
// ---------------------------------------------------------------------------
__global__ __launch_bounds__(256) void gemm64_bf16x3(
    const unsigned short* __restrict__ Ah, const unsigned short* __restrict__ Al,
    const unsigned short* __restrict__ Bh, const unsigned short* __restrict__ Bl,
    const float* __restrict__ bias_lo, const float* __restrict__ bias_hi,
    float* __restrict__ Cf, unsigned short* __restrict__ Chi,
    unsigned short* __restrict__ Clo, int M, int N, int Kd, int split_col)
{
    __shared__ unsigned short sAh[64 * 72], sAl[64 * 72];
    __shared__ unsigned short sBh[64 * 72], sBl[64 * 72];
    int tid = threadIdx.x;
    int lane = tid & 63, wv = tid >> 6;
    int wr = wv >> 1, wc = wv & 1;          // wave 32x32
    int row0 = blockIdx.y * 64, col0 = blockIdx.x * 64;

    f32x4 acc[2][2];
#pragma unroll
    for (int i = 0; i < 2; i++)
#pragma unroll
        for (int j = 0; j < 2; j++) acc[i][j] = (f32x4){0.f, 0.f, 0.f, 0.f};

    int sr = tid >> 2, sc = (tid & 3) * 16;   // row, 16-elem chunk of 64
    const unsigned short* gAh = Ah + (size_t)(row0 + sr) * Kd + sc;
    const unsigned short* gAl = Al + (size_t)(row0 + sr) * Kd + sc;
    const unsigned short* gBh = Bh + (size_t)(col0 + sr) * Kd + sc;
    const unsigned short* gBl = Bl + (size_t)(col0 + sr) * Kd + sc;
    int am = lane & 15, qk = (lane >> 4) * 8;

    for (int k0 = 0; k0 < Kd; k0 += 64) {
        __syncthreads();
        *(float4*)&sAh[sr * 72 + sc]     = *(const float4*)(gAh + k0);
        *(float4*)&sAh[sr * 72 + sc + 8] = *(const float4*)(gAh + k0 + 8);
        *(float4*)&sAl[sr * 72 + sc]     = *(const float4*)(gAl + k0);
        *(float4*)&sAl[sr * 72 + sc + 8] = *(const float4*)(gAl + k0 + 8);
        *(float4*)&sBh[sr * 72 + sc]     = *(const float4*)(gBh + k0);
        *(float4*)&sBh[sr * 72 + sc + 8] = *(const float4*)(gBh + k0 + 8);
        *(float4*)&sBl[sr * 72 + sc]     = *(const float4*)(gBl + k0);
        *(float4*)&sBl[sr * 72 + sc + 8] = *(const float4*)(gBl + k0 + 8);
        __syncthreads();

#pragma unroll
        for (int ks = 0; ks < 2; ks++) {
            bf16x8 ah[2], al[2], bh[2], bl[2];
#pragma unroll
            for (int rt = 0; rt < 2; rt++) {
                int r = wr * 32 + rt * 16 + am;
                ah[rt] = *(const bf16x8*)&sAh[r * 72 + ks * 32 + qk];
                al[rt] = *(const bf16x8*)&sAl[r * 72 + ks * 32 + qk];
            }
#pragma unroll
            for (int ct = 0; ct < 2; ct++) {
                int c = wc * 32 + ct * 16 + am;
                bh[ct] = *(const bf16x8*)&sBh[c * 72 + ks * 32 + qk];
                bl[ct] = *(const bf16x8*)&sBl[c * 72 + ks * 32 + qk];
            }
#pragma unroll
            for (int rt = 0; rt < 2; rt++)
#pragma unroll
                for (int ct = 0; ct < 2; ct++) {
                    acc[rt][ct] = __builtin_amdgcn_mfma_f32_16x16x32_bf16(ah[rt], bh[ct], acc[rt][ct], 0, 0, 0);
                    acc[rt][ct] = __builtin_amdgcn_mfma_f32_16x16x32_bf16(ah[rt], bl[ct], acc[rt][ct], 0, 0, 0);
                    acc[rt][ct] = __builtin_amdgcn_mfma_f32_16x16x32_bf16(al[rt], bh[ct], acc[rt][ct], 0, 0, 0);
                }
        }
    }

    int rq = (lane >> 4) * 4;
#pragma unroll
    for (int rt = 0; rt < 2; rt++)
#pragma unroll
        for (int ct = 0; ct < 2; ct++) {
            int col = col0 + wc * 32 + ct * 16 + am;
#pragma unroll
            for (int rg = 0; rg < 4; rg++) {
                int row = row0 + wr * 32 + rt * 16 + rq + rg;
                float v = acc[rt][ct][rg];
                if (col < split_col) {
                    if (bias_lo) v += bias_lo[col];
                    size_t idx = (size_t)row * split_col + col;
                    unsigned short hh = f2bf(v);
                    Chi[idx] = hh;
                    Clo[idx] = f2bf(v - bf2f(hh));
                } else {
                    if (bias_hi) v += bias_hi[col - split_col];
                    Cf[(size_t)row * (N - split_col) + col - split_col] = v;
                }
            }
        }
}

// ---------------------------------------------------------------------------
// RoPE applied in-place to q and k slices of qkv[S,3072].
// ---------------------------------------------------------------------------
__global__ __launch_bounds__(256) void rope_kernel(
    float* __restrict__ qkv, const float* __restrict__ rope)
{
    int idx = blockIdx.x * blockDim.x + threadIdx.x;  // S*H*32 total
    if (idx >= S_ * H_ * 32) return;
    int d = idx & 31;
    int h = (idx >> 5) & (H_ - 1);
    int s = idx >> 9;
    float r = rope[s * 32 + d];
    float c = cosf(r), sn = sinf(r);
    size_t base = (size_t)s * 3072 + h * 64 + d;
    float q1 = qkv[base], q2 = qkv[base + 32];
    qkv[base]      = q1 * c - q2 * sn;
    qkv[base + 32] = q2 * c + q1 * sn;
    float k1 = qkv[base + 1024], k2 = qkv[base + 1024 + 32];
    qkv[base + 1024]      = k1 * c - k2 * sn;
    qkv[base + 1024 + 32] = k2 * c + k1 * sn;
}

// ---------------------------------------------------------------------------
// Fused index scores + top-K membership (R12-exact: 4 rows/block, 512 blocks,
// measured 42.5 us; best of the R12-R15 variants — 4-way select parallelism).
// ---------------------------------------------------------------------------
__global__ __launch_bounds__(256) void score_topk_kernel(
    const float* __restrict__ qIk,
    const int* __restrict__ coords, const float* __restrict__ rpe_table,
    const float* __restrict__ W1g, const float* __restrict__ b1g,
    const float* __restrict__ W2g, const float* __restrict__ b2g,
    unsigned* __restrict__ selmask)
{
    __shared__ float skI[64][132];
    __shared__ float sqI2[4][IDH2_];
    __shared__ unsigned skeys[4][LI_];
    __shared__ int shist[4][256];
    __shared__ float srpe[NBUCK_ * IH_];
    __shared__ float sW1[GH_ * IH_], sb1[GH_], sW2[IH_ * GH_], sb2[IH_];

    int tid  = threadIdx.x;
    int lane = tid & 63;
    int wv   = tid >> 6;
    int row  = blockIdx.x * 4 + wv;
    int n    = (blockIdx.x * 4) >> 9;

    for (int i = tid; i < NBUCK_ * IH_; i += 256) srpe[i] = rpe_table[i];
    if (tid < 32) sW1[tid] = W1g[tid];
    else if (tid < 64) sW2[tid - 32] = W2g[tid - 32];
    else if (tid < 72) sb1[tid - 64] = b1g[tid - 64];
    else if (tid < 76) sb2[tid - 72] = b2g[tid - 72];
    for (int i = tid; i < 4 * IDH2_; i += 256)
        sqI2[i >> 7][i & 127] =
            qIk[(size_t)(blockIdx.x * 4 + (i >> 7)) * 256 + (i & 127)];
    int pq = coords[row * 2 + 1];

    for (int kt = 0; kt < 8; kt++) {
        __syncthreads();
        {
            int r  = tid >> 2;
            int d0 = (tid & 3) * 32;
            const float* src = qIk + (size_t)(n * LI_ + kt * 64 + r) * 256 + 128 + d0;
#pragma unroll
            for (int j = 0; j < 8; j++)
                *(float4*)&skI[r][d0 + j * 4] = *(const float4*)(src + j * 4);
        }
        __syncthreads();

        int kloc = lane;
        int kg   = kt * 64 + kloc;
        const float* sq = &sqI2[wv][0];
        float dh[8];
#pragma unroll
        for (int hh = 0; hh < 8; hh++) {
            float acc = 0.0f;
#pragma unroll
            for (int d = 0; d < 16; d += 4) {
                float4 kv = *(const float4*)&skI[kloc][hh * 16 + d];
                acc += sq[hh * 16 + d + 0] * kv.x + sq[hh * 16 + d + 1] * kv.y +
                       sq[hh * 16 + d + 2] * kv.z + sq[hh * 16 + d + 3] * kv.w;
            }
            dh[hh] = acc;
        }
        int pk = coords[(n * LI_ + kg) * 2 + 1];
        int rel = pq - pk;
        rel = rel < -MAXREL_ ? -MAXREL_ : (rel > MAXREL_ ? MAXREL_ : rel);
        const float* rp = srpe + (rel + MAXREL_) * IH_;
        float t1[GH_];
#pragma unroll
        for (int g = 0; g < GH_; g++) t1[g] = sb1[g];
#pragma unroll
        for (int j = 0; j < IH_; j++) {
            float gate = dh[IH_ + j] + rp[j];
#pragma unroll
            for (int g = 0; g < GH_; g++) t1[g] += gate * sW1[g * IH_ + j];
        }
#pragma unroll
        for (int g = 0; g < GH_; g++) t1[g] = fmaxf(t1[g], 0.0f);
        float score = 0.0f;
#pragma unroll
        for (int j = 0; j < IH_; j++) {
            float t2 = sb2[j];
#pragma unroll
            for (int g = 0; g < GH_; g++) t2 += t1[g] * sW2[j * GH_ + g];
            float sg = 1.0f / (1.0f + expf(-t2));
            float rs = fmaxf(dh[j] + rp[j], 0.0f);
            score += rs * sg;
        }
        unsigned bits = __float_as_uint(score);
        skeys[wv][kg] = (bits & 0x80000000u) ? ~bits : (bits | 0x80000000u);
    }
    __syncthreads();

    unsigned pref = 0u;
    int kcur = K_;
    const unsigned himask[4] = {0u, 0xFF000000u, 0xFFFF0000u, 0xFFFFFF00u};
#pragma unroll
    for (int pass = 0; pass < 4; pass++) {
        int shift = 24 - pass * 8;
        unsigned hm = himask[pass];
        *(int4*)&shist[wv][4 * lane] = make_int4(0, 0, 0, 0);
        __syncthreads();
#pragma unroll
        for (int c = 0; c < 8; c++) {
            unsigned key = skeys[wv][c * 64 + lane];
            if ((key & hm) == pref) atomicAdd(&shist[wv][(key >> shift) & 255], 1);
        }
        __syncthreads();
        int4 b4 = *(const int4*)&shist[wv][4 * lane];
        int b[4] = {b4.x, b4.y, b4.z, b4.w};
        int t = b[0] + b[1] + b[2] + b[3];
        int Ssum = t;
#pragma unroll
        for (int off = 1; off < 64; off <<= 1) {
            int u = __shfl_down(Ssum, off, 64);
            if (lane + off < 64) Ssum += u;
        }
        int E = Ssum - t;
        int cs[5];
        cs[4] = E;
        cs[3] = b[3] + E;
        cs[2] = b[2] + cs[3];
        cs[1] = b[1] + cs[2];
        cs[0] = b[0] + cs[1];
        bool found = false;
        unsigned cpref = 0u; int ck = 0;
#pragma unroll
        for (int j = 0; j < 4; j++) {
            if (!found && cs[j] >= kcur && cs[j + 1] < kcur) {
                found = true;
                cpref = pref | ((unsigned)(4 * lane + j) << shift);
                ck = kcur - cs[j + 1];
            }
        }
        unsigned long long bm = __ballot(found);
        int src = __ffsll((long long)bm) - 1;
        pref = (unsigned)__shfl((int)cpref, src, 64);
        kcur = __shfl(ck, src, 64);
        __syncthreads();
    }
    unsigned Tu = pref;

    unsigned long long bg[8], be[8];
#pragma unroll
    for (int c = 0; c < 8; c++) {
        unsigned key = skeys[wv][c * 64 + lane];
        bg[c] = __ballot(key > Tu);
        be[c] = __ballot(key == Tu);
    }
    if (lane < 16) {
        int total_gt = 0;
#pragma unroll
        for (int c = 0; c < 8; c++) total_gt += __popcll(bg[c]);
        int base = 0;
#pragma unroll
        for (int c = 0; c < 8; c++) {
            if (2 * c < lane)     base += __popc((unsigned)be[c]);
            if (2 * c + 1 < lane) base += __popc((unsigned)(be[c] >> 32));
        }
        unsigned gw = (unsigned)(bg[lane >> 1] >> (32 * (lane & 1)));
        unsigned ew = (unsigned)(be[lane >> 1] >> (32 * (lane & 1)));
        int ne = K_ - total_gt - base;
        int pc = __popc(ew);
        int m = ne < 0 ? 0 : (ne > pc ? pc : ne);
        while (pc > m) { ew ^= (1u << (31 - __clz(ew))); pc--; }
        selmask[(size_t)row * 16 + lane] = gw | ew;
    }
}

// ---------------------------------------------------------------------------
// Dense-masked attention v4: full MFMA bf16x3 (R12/R14-passing, unchanged).
// ---------------------------------------------------------------------------
__global__ __launch_bounds__(256) void attn_kernel(
    const float* __restrict__ qkv, const unsigned* __restrict__ selmask,
    unsigned short* __restrict__ outh, unsigned short* __restrict__ outl)
{
    __shared__ unsigned short Qh[64 * 72],  Ql[64 * 72];   // [q][d]
    __shared__ unsigned short KPh[64 * 72], KPl[64 * 72];  // K [key][d] -> P [q][key]
    __shared__ unsigned short VTh[64 * 72], VTl[64 * 72];  // V^T [d][key]
    __shared__ unsigned Ms[64][16];

    int b  = blockIdx.x;
    int qt = b >> 6;                 // XCD swizzle: qt in high bits
    int nh = b & 63;
    int h  = nh & 15;
    int n  = nh >> 4;
    int tid = threadIdx.x;
    int lane = tid & 63, w = tid >> 6;
    int lane15 = lane & 15, quad = lane >> 4;
    int q0 = n * LI_ + qt * 64;

    for (int i = tid; i < 64 * 16; i += 256)
        Ms[i >> 4][i & 15] = selmask[(size_t)(q0 + (i >> 4)) * 16 + (i & 15)];

    // stage Q once: row r, 16 d's; scale 1/8 then split (exact scaling)
    {
        int r = tid >> 2, c0 = (tid & 3) * 16;
        const float* src = qkv + (size_t)(q0 + r) * 3072 + h * 64 + c0;
        unsigned short hb[16], lb[16];
#pragma unroll
        for (int j = 0; j < 16; j += 4) {
            float4 v = *(const float4*)(src + j);
            float f[4] = {v.x * 0.125f, v.y * 0.125f, v.z * 0.125f, v.w * 0.125f};
#pragma unroll
            for (int t = 0; t < 4; t++) {
                unsigned short hh = f2bf(f[t]);
                hb[j + t] = hh;
                lb[j + t] = f2bf(f[t] - bf2f(hh));
            }
        }
        *(uint4*)&Qh[r * 72 + c0]     = *(uint4*)&hb[0];
        *(uint4*)&Qh[r * 72 + c0 + 8] = *(uint4*)&hb[8];
        *(uint4*)&Ql[r * 72 + c0]     = *(uint4*)&lb[0];
        *(uint4*)&Ql[r * 72 + c0 + 8] = *(uint4*)&lb[8];
    }

    f32x4 o_acc[4];
#pragma unroll
    for (int i = 0; i < 4; i++) o_acc[i] = (f32x4){0.f, 0.f, 0.f, 0.f};
    float rsum[4] = {};

    for (int kt = 0; kt < 8; kt++) {
        __syncthreads();   // prev PV reads of KP/VT done
        // stage K [key][d] hi/lo
        {
            int r = tid >> 2, c0 = (tid & 3) * 16;
            const float* src = qkv + (size_t)(n * LI_ + kt * 64 + r) * 3072 + 1024 + h * 64 + c0;
            unsigned short hb[16], lb[16];
#pragma unroll
            for (int j = 0; j < 16; j += 4) {
                float4 v = *(const float4*)(src + j);
                float f[4] = {v.x, v.y, v.z, v.w};
#pragma unroll
                for (int t = 0; t < 4; t++) {
                    unsigned short hh = f2bf(f[t]);
                    hb[j + t] = hh;
                    lb[j + t] = f2bf(f[t] - bf2f(hh));
                }
            }
            *(uint4*)&KPh[r * 72 + c0]     = *(uint4*)&hb[0];
            *(uint4*)&KPh[r * 72 + c0 + 8] = *(uint4*)&hb[8];
            *(uint4*)&KPl[r * 72 + c0]     = *(uint4*)&lb[0];
            *(uint4*)&KPl[r * 72 + c0 + 8] = *(uint4*)&lb[8];
        }
        // stage V^T [d][key]
        {
            int d = lane;
            int k0 = w * 16;
            const float* src = qkv + (size_t)(n * LI_ + kt * 64 + k0) * 3072 + 2048 + h * 64 + d;
            unsigned short hb[16], lb[16];
#pragma unroll
            for (int j = 0; j < 16; j++) {
                float f = src[(size_t)j * 3072];
                unsigned short hh = f2bf(f);
                hb[j] = hh;
                lb[j] = f2bf(f - bf2f(hh));
            }
            *(uint4*)&VTh[d * 72 + k0]     = *(uint4*)&hb[0];
            *(uint4*)&VTh[d * 72 + k0 + 8] = *(uint4*)&hb[8];
            *(uint4*)&VTl[d * 72 + k0]     = *(uint4*)&lb[0];
            *(uint4*)&VTl[d * 72 + k0 + 8] = *(uint4*)&lb[8];
        }
        __syncthreads();

        // QK: wave w computes q-tile w vs all 4 key-tiles, bf16x3
        f32x4 s_acc[4];
#pragma unroll
        for (int nt = 0; nt < 4; nt++) s_acc[nt] = (f32x4){0.f, 0.f, 0.f, 0.f};
        {
            bf16x8 qfh[2], qfl[2];
#pragma unroll
            for (int ks = 0; ks < 2; ks++) {
                qfh[ks] = *(const bf16x8*)&Qh[(16 * w + lane15) * 72 + ks * 32 + quad * 8];
                qfl[ks] = *(const bf16x8*)&Ql[(16 * w + lane15) * 72 + ks * 32 + quad * 8];
            }
#pragma unroll
            for (int nt = 0; nt < 4; nt++) {
#pragma unroll
                for (int ks = 0; ks < 2; ks++) {
                    bf16x8 kfh = *(const bf16x8*)&KPh[(16 * nt + lane15) * 72 + ks * 32 + quad * 8];
                    bf16x8 kfl = *(const bf16x8*)&KPl[(16 * nt + lane15) * 72 + ks * 32 + quad * 8];
                    s_acc[nt] = __builtin_amdgcn_mfma_f32_16x16x32_bf16(qfh[ks], kfh, s_acc[nt], 0, 0, 0);
                    s_acc[nt] = __builtin_amdgcn_mfma_f32_16x16x32_bf16(qfh[ks], kfl, s_acc[nt], 0, 0, 0);
                    s_acc[nt] = __builtin_amdgcn_mfma_f32_16x16x32_bf16(qfl[ks], kfh, s_acc[nt], 0, 0, 0);
                }
            }
        }
        __syncthreads();   // all K frag reads done before P overwrite

        // softmax (C-layout: row q = quad*4+reg, col key = lane15) + P split
#pragma unroll
        for (int nt = 0; nt < 4; nt++) {
            int kb = kt * 64 + nt * 16 + lane15;
            int wi = kb >> 5, bit = kb & 31;
#pragma unroll
            for (int reg = 0; reg < 4; reg++) {
                int qloc = 16 * w + quad * 4 + reg;
                unsigned mw = Ms[qloc][wi];
                float p = ((mw >> bit) & 1u) ? __expf(s_acc[nt][reg]) : 0.0f;
                rsum[reg] += p;
                unsigned short ph = f2bf(p);
                KPh[qloc * 72 + nt * 16 + lane15] = ph;
                KPl[qloc * 72 + nt * 16 + lane15] = f2bf(p - bf2f(ph));
            }
        }
        __syncthreads();

        // PV: A = P [q][key], B = V^T [d][key], bf16x3
        {
            bf16x8 pfh[2], pfl[2];
#pragma unroll
            for (int ks = 0; ks < 2; ks++) {
                pfh[ks] = *(const bf16x8*)&KPh[(16 * w + lane15) * 72 + ks * 32 + quad * 8];
                pfl[ks] = *(const bf16x8*)&KPl[(16 * w + lane15) * 72 + ks * 32 + quad * 8];
            }
#pragma unroll
            for (int dt = 0; dt < 4; dt++) {
#pragma unroll
                for (int ks = 0; ks < 2; ks++) {
                    bf16x8 vfh = *(const bf16x8*)&VTh[(16 * dt + lane15) * 72 + ks * 32 + quad * 8];
                    bf16x8 vfl = *(const bf16x8*)&VTl[(16 * dt + lane15) * 72 + ks * 32 + quad * 8];
                    o_acc[dt] = __builtin_amdgcn_mfma_f32_16x16x32_bf16(pfh[ks], vfh, o_acc[dt], 0, 0, 0);
                    o_acc[dt] = __builtin_amdgcn_mfma_f32_16x16x32_bf16(pfh[ks], vfl, o_acc[dt], 0, 0, 0);
                    o_acc[dt] = __builtin_amdgcn_mfma_f32_16x16x32_bf16(pfl[ks], vfh, o_acc[dt], 0, 0, 0);
                }
            }
        }
    }

    // row sums: reduce over the 16 lanes (lane15) sharing each q row
#pragma unroll
    for (int reg = 0; reg < 4; reg++) {
        rsum[reg] += __shfl_xor(rsum[reg], 1, 64);
        rsum[reg] += __shfl_xor(rsum[reg], 2, 64);
        rsum[reg] += __shfl_xor(rsum[reg], 4, 64);
        rsum[reg] += __shfl_xor(rsum[reg], 8, 64);
    }

    // epilogue: normalize, split hi/lo, store (C-layout: row=quad*4+reg, col=lane15)
#pragma unroll
    for (int dt = 0; dt < 4; dt++) {
#pragma unroll
        for (int reg = 0; reg < 4; reg++) {
            float v = o_acc[dt][reg] / rsum[reg];
            size_t ob = (size_t)(q0 + 16 * w + quad * 4 + reg) * 1024 + h * 64 + 16 * dt + lane15;
            unsigned short hh = f2bf(v);
            outh[ob] = hh;
            outl[ob] = f2bf(v - bf2f(hh));
        }
    }
}

// ---------------------------------------------------------------------------
extern "C" void kernel_launch(void* const* d_in, const int* in_sizes, int n_in,
                              void* d_out, int out_size, void* d_ws, size_t ws_size,
                              hipStream_t stream)
{
    const float* hidden  = (const float*)d_in[0];
    const int*   coords  = (const int*)d_in[1];
    const float* rope    = (const float*)d_in[3];
    const float* Wq_idx  = (const float*)d_in[4];
    const float* Wk_idx  = (const float*)d_in[5];
    const float* W1g     = (const float*)d_in[6];
    const float* b1g     = (const float*)d_in[7];
    const float* W2g     = (const float*)d_in[8];
    const float* b2g     = (const float*)d_in[9];
    const float* rpe     = (const float*)d_in[10];
    const float* Wqkv_d  = (const float*)d_in[11];
    const float* bqkv_d  = (const float*)d_in[12];
    const float* Wqkv_u  = (const float*)d_in[13];
    const float* bqkv_u  = (const float*)d_in[14];
    const float* Wp_d    = (const float*)d_in[15];
    const float* bp_d    = (const float*)d_in[16];
    const float* Wp_u    = (const float*)d_in[17];
    const float* bp_u    = (const float*)d_in[18];
    const float* scaler  = (const float*)d_in[19];
    float* out = (float*)d_out;

    unsigned short* sp_hi  = (unsigned short*)d_ws;
    unsigned short* sp_lo  = sp_hi + NSPLIT_;
    unsigned short* mid_hi = sp_lo + NSPLIT_;
    unsigned short* mid_lo = mid_hi + (size_t)S_ * BOT_;
    float* qkv = (float*)(mid_lo + (size_t)S_ * BOT_);
    float* qIk = qkv + (size_t)S_ * 3 * DIM_;
    unsigned* selmask = (unsigned*)(qIk + (size_t)S_ * 256);

    // 0) split hidden + all weights into hi/lo bf16
    split_all_kernel<<<(NSPLIT_ / 4 + 255) / 256, 256, 0, stream>>>(
        hidden, Wqkv_d, Wq_idx, Wk_idx, Wqkv_u, Wp_d, Wp_u, sp_hi, sp_lo);

    // 1) fused gemm1: hidden @ [Wqkv_d;Wq;Wk]^T -> mid(hi/lo) + qIk(fp32)
    gemm64_bf16x3<<<dim3(512 / 64, S_ / 64), 256, 0, stream>>>(
        sp_hi, sp_lo, sp_hi + OFF_W1_, sp_lo + OFF_W1_,
        bqkv_d, nullptr, qIk, mid_hi, mid_lo, S_, 512, DIM_, 256);

    // 2) qkv = mid @ Wqkv_u^T + b (fp32)
    gemm_bf16x3<<<dim3(3 * DIM_ / 64, S_ / 128), 256, 0, stream>>>(
        mid_hi, mid_lo, sp_hi + OFF_WQKVU_, sp_lo + OFF_WQKVU_,
        bqkv_u, nullptr, qkv, S_, 3 * DIM_, BOT_);

    // 3) RoPE on q,k in place
    rope_kernel<<<(S_ * H_ * 32) / 256, 256, 0, stream>>>(qkv, rope);

    // 4) fused index scores + top-k membership (R12: 4 rows/block)
    score_topk_kernel<<<S_ / 4, 256, 0, stream>>>(
        qIk, coords, rpe, W1g, b1g, W2g, b2g, selmask);

    // 5) MFMA attention (emits attout hi/lo into hidden's split slots)
    attn_kernel<<<NIMG_ * H_ * 8, 256, 0, stream>>>(qkv, selmask, sp_hi, sp_lo);

    // 6) mid2 = attout @ Wp_d^T + b (hi/lo)
    gemm64_bf16x3<<<dim3(BOT_ / 64, S_ / 64), 256, 0, stream>>>(
        sp_hi, sp_lo, sp_hi + OFF_WPD_, sp_lo + OFF_WPD_,
        bp_d, nullptr, nullptr, mid_hi, mid_lo, S_, BOT_, DIM_, BOT_);

    // 7) out = mid2 @ Wp_u^T + b, *scaler (fp32)
    gemm_bf16x3<<<dim3(DIM_ / 64, S_ / 128), 256, 0, stream>>>(
        mid_hi, mid_lo, sp_hi + OFF_WPU_, sp_lo + OFF_WPU_,
        bp_u, scaler, out, S_, DIM_, BOT_);
}